// Round 2
// baseline (710.922 us; speedup 1.0000x reference)
//
#include <hip/hip_runtime.h>
#include <hip/hip_bf16.h>

typedef unsigned short u16;
typedef __attribute__((ext_vector_type(8))) short short8;
typedef __attribute__((ext_vector_type(4))) float f32x4;

#define B_   4
#define S_   1024
#define D_   1024
#define H_   16
#define DH_  64
#define NOUT_ ((size_t)B_ * S_ * D_)   // 4,194,304 elements (out); attn follows

__device__ __forceinline__ float b2f(u16 u) {
  union { unsigned int u; float f; } v; v.u = ((unsigned int)u) << 16; return v.f;
}
__device__ __forceinline__ u16 f2b(float f) {
  __hip_bfloat16 h = __float2bfloat16(f);
  return *reinterpret_cast<u16*>(&h);
}

// K0: dtype sniffer. fp32 low-halves read as bf16 hit exponent 0xFF w.p.
// ~1/256 per u16 (certain over 64K samples); bf16 N(0,1) data never does.
__global__ __launch_bounds__(256) void sniff_kernel(const u16* __restrict__ q,
                                                    int* __restrict__ flag) {
  __shared__ int s_hit;
  if (threadIdx.x == 0) s_hit = 0;
  __syncthreads();
  int hit = 0;
  for (int i = threadIdx.x; i < 65536; i += 256)
    if ((q[i] & 0x7F80u) == 0x7F80u) hit = 1;
  if (hit) atomicOr(&s_hit, 1);
  __syncthreads();
  if (threadIdx.x == 0) *flag = s_hit;
}

// Stage a 64x64 tile (rows base.., cols kc..) of a row-major [*,1024] matrix
// into LDS as bf16, honoring the runtime dtype flag.
__device__ __forceinline__ void stage_tile(u16 (*dst)[72], const void* src,
                                           int base, int kc, int t, bool is32) {
  const int lr = t >> 3;
  const int lk = (t & 7) * 8;
  if (is32) {
    const float* S = (const float*)src;
#pragma unroll
    for (int i = 0; i < 2; i++) {
      int r = lr + 32 * i;
      const float* p = &S[(size_t)(base + r) * 1024 + kc + lk];
      f32x4 f0 = *(const f32x4*)p;
      f32x4 f1 = *(const f32x4*)(p + 4);
      short8 s;
      s[0] = (short)f2b(f0[0]); s[1] = (short)f2b(f0[1]);
      s[2] = (short)f2b(f0[2]); s[3] = (short)f2b(f0[3]);
      s[4] = (short)f2b(f1[0]); s[5] = (short)f2b(f1[1]);
      s[6] = (short)f2b(f1[2]); s[7] = (short)f2b(f1[3]);
      *(short8*)&dst[r][lk] = s;
    }
  } else {
    const u16* S = (const u16*)src;
#pragma unroll
    for (int i = 0; i < 2; i++) {
      int r = lr + 32 * i;
      *(short8*)&dst[r][lk] = *(const short8*)&S[(size_t)(base + r) * 1024 + kc + lk];
    }
  }
}

// K1: fused Q/K/V projection GEMM -> ws [B,H,S,64] bf16.
__global__ __launch_bounds__(256) void proj_kernel(
    const void* __restrict__ q, const void* __restrict__ k, const void* __restrict__ v,
    const void* __restrict__ Wq, const void* __restrict__ Wk, const void* __restrict__ Wv,
    const int* __restrict__ flag,
    u16* __restrict__ qh, u16* __restrict__ kh, u16* __restrict__ vh)
{
  __shared__ u16 sA[64][72];
  __shared__ u16 sB[64][72];
  const int t = threadIdx.x;
  const int w = t >> 6, ln = t & 15, quad = (t & 63) >> 4;
  const int bx = blockIdx.x;
  const int z  = bx >> 4;
  const int n0 = (bx & 15) * 64;
  const int m0 = blockIdx.y * 64;
  const bool is32 = (*flag != 0);
  const void* A = (z == 0) ? q : (z == 1) ? k : v;
  const void* W = (z == 0) ? Wq : (z == 1) ? Wk : Wv;
  u16* Out      = (z == 0) ? qh : (z == 1) ? kh : vh;

  f32x4 acc[4] = {};
  for (int kc = 0; kc < 1024; kc += 64) {
    stage_tile(sA, A, m0, kc, t, is32);
    stage_tile(sB, W, n0, kc, t, is32);
    __syncthreads();
    short8 a0 = *(const short8*)&sA[w * 16 + ln][quad * 8];
    short8 a1 = *(const short8*)&sA[w * 16 + ln][32 + quad * 8];
#pragma unroll
    for (int nt = 0; nt < 4; nt++) {
      short8 b0 = *(const short8*)&sB[nt * 16 + ln][quad * 8];
      short8 b1 = *(const short8*)&sB[nt * 16 + ln][32 + quad * 8];
      acc[nt] = __builtin_amdgcn_mfma_f32_16x16x32_bf16(a0, b0, acc[nt], 0, 0, 0);
      acc[nt] = __builtin_amdgcn_mfma_f32_16x16x32_bf16(a1, b1, acc[nt], 0, 0, 0);
    }
    __syncthreads();
  }
#pragma unroll
  for (int nt = 0; nt < 4; nt++) {
#pragma unroll
    for (int r = 0; r < 4; r++) {
      int m = m0 + w * 16 + quad * 4 + r;
      int n = n0 + nt * 16 + ln;
      int b = m >> 10, s = m & 1023;
      int h = n >> 6,  d = n & 63;
      Out[((size_t)((b * H_ + h) * S_ + s)) * DH_ + d] = f2b(acc[nt][r]);
    }
  }
}

// K2: vh [BH,S,64] -> vhT [BH,64,S]
__global__ __launch_bounds__(256) void transpose_v(
    const u16* __restrict__ vh, u16* __restrict__ vhT)
{
  __shared__ u16 sT[64][80];
  const int t  = threadIdx.x;
  const int bh = blockIdx.y;
  const int s0 = blockIdx.x * 64;
#pragma unroll
  for (int i = 0; i < 2; i++) {
    int r = (t >> 3) + 32 * i, d0 = (t & 7) * 8;
    *(short8*)&sT[r][d0] = *(const short8*)&vh[((size_t)bh * S_ + s0 + r) * DH_ + d0];
  }
  __syncthreads();
#pragma unroll
  for (int i = 0; i < 2; i++) {
    int d = (t >> 3) + 32 * i, c0 = (t & 7) * 8;
    short8 val;
#pragma unroll
    for (int j = 0; j < 8; j++) val[j] = (short)sT[c0 + j][d];
    *(short8*)&vhT[((size_t)bh * DH_ + d) * S_ + s0 + c0] = val;
  }
}

// K3: attention per (b,h, 16 q-rows): QK^T -> mask+softmax -> attn out + PV.
__global__ __launch_bounds__(256) void attn_kernel(
    const u16* __restrict__ qh, const u16* __restrict__ kh,
    const u16* __restrict__ vhT, const int* __restrict__ mask,
    const int* __restrict__ flag, void* __restrict__ d_out_base,
    u16* __restrict__ ctx)
{
  __shared__ u16 s_p[16][1040];
  __shared__ u16 s_kv[64][72];
  __shared__ u16 s_q[16][72];
  const int t = threadIdx.x;
  const int w = t >> 6, ln = t & 15, quad = (t & 63) >> 4;
  const int bh = blockIdx.y;
  const int b = bh >> 4;
  const int q0 = blockIdx.x * 16;
  const bool is32 = (*flag != 0);

  if (t < 128) {
    int r = t >> 3, d0 = (t & 7) * 8;
    *(short8*)&s_q[r][d0] = *(const short8*)&qh[((size_t)bh * S_ + q0 + r) * DH_ + d0];
  }
  __syncthreads();
  const short8 aq0 = *(const short8*)&s_q[ln][quad * 8];
  const short8 aq1 = *(const short8*)&s_q[ln][32 + quad * 8];

  for (int ck = 0; ck < 16; ck++) {
#pragma unroll
    for (int i = 0; i < 2; i++) {
      int r = (t >> 3) + 32 * i, d0 = (t & 7) * 8;
      *(short8*)&s_kv[r][d0] =
          *(const short8*)&kh[((size_t)bh * S_ + ck * 64 + r) * DH_ + d0];
    }
    __syncthreads();
    short8 b0 = *(const short8*)&s_kv[w * 16 + ln][quad * 8];
    short8 b1 = *(const short8*)&s_kv[w * 16 + ln][32 + quad * 8];
    f32x4 acc = {};
    acc = __builtin_amdgcn_mfma_f32_16x16x32_bf16(aq0, b0, acc, 0, 0, 0);
    acc = __builtin_amdgcn_mfma_f32_16x16x32_bf16(aq1, b1, acc, 0, 0, 0);
    int col = ck * 64 + w * 16 + ln;
#pragma unroll
    for (int r = 0; r < 4; r++)
      s_p[quad * 4 + r][col] = f2b(acc[r] * 0.03125f);
    __syncthreads();
  }

  {
    const int r = t >> 4, c0 = t & 15;
    const int* mrow = mask + ((size_t)b * S_ + q0 + r) * S_;
    float m = -3.0e38f;
    for (int i = 0; i < 64; i++) {
      int c = c0 + 16 * i;
      float sv = b2f(s_p[r][c]);
      if (mrow[c]) { sv = -3.0e38f; s_p[r][c] = f2b(-3.0e38f); }
      m = fmaxf(m, sv);
    }
#pragma unroll
    for (int off = 8; off >= 1; off >>= 1) m = fmaxf(m, __shfl_xor(m, off));
    float l = 0.f;
    for (int i = 0; i < 64; i++) {
      int c = c0 + 16 * i;
      float p = __expf(b2f(s_p[r][c]) - m);
      l += p;
      s_p[r][c] = f2b(p);
    }
#pragma unroll
    for (int off = 8; off >= 1; off >>= 1) l += __shfl_xor(l, off);
    float rinv = 1.0f / l;
    const size_t rowoff = NOUT_ + ((size_t)bh * S_ + q0 + r) * S_;
    if (is32) {
      float* arow = (float*)d_out_base + rowoff;
      for (int i = 0; i < 64; i++) {
        int c = c0 + 16 * i;
        float pv = b2f(s_p[r][c]) * rinv;
        s_p[r][c] = f2b(pv);
        arow[c] = pv;
      }
    } else {
      u16* arow = (u16*)d_out_base + rowoff;
      for (int i = 0; i < 64; i++) {
        int c = c0 + 16 * i;
        u16 a16 = f2b(b2f(s_p[r][c]) * rinv);
        s_p[r][c] = a16;
        arow[c] = a16;
      }
    }
  }
  __syncthreads();

  f32x4 accC = {};
  const int n0 = w * 16;
  for (int ck = 0; ck < 16; ck++) {
#pragma unroll
    for (int i = 0; i < 2; i++) {
      int d = (t >> 3) + 32 * i, k0 = (t & 7) * 8;
      *(short8*)&s_kv[d][k0] =
          *(const short8*)&vhT[((size_t)bh * DH_ + d) * S_ + ck * 64 + k0];
    }
    __syncthreads();
    short8 ap0 = *(const short8*)&s_p[ln][ck * 64 + quad * 8];
    short8 ap1 = *(const short8*)&s_p[ln][ck * 64 + 32 + quad * 8];
    short8 bv0 = *(const short8*)&s_kv[n0 + ln][quad * 8];
    short8 bv1 = *(const short8*)&s_kv[n0 + ln][32 + quad * 8];
    accC = __builtin_amdgcn_mfma_f32_16x16x32_bf16(ap0, bv0, accC, 0, 0, 0);
    accC = __builtin_amdgcn_mfma_f32_16x16x32_bf16(ap1, bv1, accC, 0, 0, 0);
    __syncthreads();
  }
#pragma unroll
  for (int r = 0; r < 4; r++) {
    int qrow = q0 + quad * 4 + r;
    int h = bh & 15;
    ctx[((size_t)b * S_ + qrow) * D_ + h * DH_ + n0 + ln] = f2b(accC[r]);
  }
}

// K4: out = ctx @ Wd^T + bd
__global__ __launch_bounds__(256) void outproj_kernel(
    const u16* __restrict__ ctx, const void* __restrict__ Wd,
    const void* __restrict__ bd, const int* __restrict__ flag,
    void* __restrict__ out)
{
  __shared__ u16 sA[64][72];
  __shared__ u16 sB[64][72];
  const int t = threadIdx.x;
  const int w = t >> 6, ln = t & 15, quad = (t & 63) >> 4;
  const int n0 = blockIdx.x * 64;
  const int m0 = blockIdx.y * 64;
  const bool is32 = (*flag != 0);

  f32x4 acc[4] = {};
  const int lr = t >> 3;
  const int lk = (t & 7) * 8;
  for (int kc = 0; kc < 1024; kc += 64) {
#pragma unroll
    for (int i = 0; i < 2; i++) {
      int r = lr + 32 * i;
      *(short8*)&sA[r][lk] = *(const short8*)&ctx[(size_t)(m0 + r) * 1024 + kc + lk];
    }
    stage_tile(sB, Wd, n0, kc, t, is32);
    __syncthreads();
    short8 a0 = *(const short8*)&sA[w * 16 + ln][quad * 8];
    short8 a1 = *(const short8*)&sA[w * 16 + ln][32 + quad * 8];
#pragma unroll
    for (int nt = 0; nt < 4; nt++) {
      short8 b0 = *(const short8*)&sB[nt * 16 + ln][quad * 8];
      short8 b1 = *(const short8*)&sB[nt * 16 + ln][32 + quad * 8];
      acc[nt] = __builtin_amdgcn_mfma_f32_16x16x32_bf16(a0, b0, acc[nt], 0, 0, 0);
      acc[nt] = __builtin_amdgcn_mfma_f32_16x16x32_bf16(a1, b1, acc[nt], 0, 0, 0);
    }
    __syncthreads();
  }
#pragma unroll
  for (int nt = 0; nt < 4; nt++) {
#pragma unroll
    for (int r = 0; r < 4; r++) {
      int m = m0 + w * 16 + quad * 4 + r;
      int n = n0 + nt * 16 + ln;
      float bv = is32 ? ((const float*)bd)[n] : b2f(((const u16*)bd)[n]);
      float val = acc[nt][r] + bv;
      if (is32) ((float*)out)[(size_t)m * 1024 + n] = val;
      else      ((u16*)out)[(size_t)m * 1024 + n] = f2b(val);
    }
  }
}

extern "C" void kernel_launch(void* const* d_in, const int* in_sizes, int n_in,
                              void* d_out, int out_size, void* d_ws, size_t ws_size,
                              hipStream_t stream) {
  const void* q    = d_in[0];
  const void* k    = d_in[1];
  const void* v    = d_in[2];
  const int*  mask = (const int*)d_in[3];
  const void* Wq   = d_in[4];
  const void* Wk   = d_in[5];
  const void* Wv   = d_in[6];
  const void* Wd   = d_in[7];
  const void* bd   = d_in[8];

  const size_t NE = NOUT_;
  u16* ws  = (u16*)d_ws;
  u16* qh  = ws;
  u16* kh  = ws + NE;
  u16* vh  = ws + 2 * NE;
  u16* vhT = ws + 3 * NE;
  u16* ctx = ws + 4 * NE;
  int* flag = (int*)((char*)d_ws + 5 * NE * sizeof(u16));

  sniff_kernel<<<1, 256, 0, stream>>>((const u16*)q, flag);
  proj_kernel<<<dim3(48, 64), 256, 0, stream>>>(q, k, v, Wq, Wk, Wv, flag, qh, kh, vh);
  transpose_v<<<dim3(16, 64), 256, 0, stream>>>(vh, vhT);
  attn_kernel<<<dim3(64, 64), 256, 0, stream>>>(qh, kh, vhT, mask, flag, d_out, ctx);
  outproj_kernel<<<dim3(16, 64), 256, 0, stream>>>(ctx, Wd, bd, flag, d_out);
}

// Round 3
// 531.802 us; speedup vs baseline: 1.3368x; 1.3368x over previous
//
#include <hip/hip_runtime.h>
#include <hip/hip_bf16.h>

typedef unsigned short u16;
typedef __attribute__((ext_vector_type(8))) short short8;
typedef __attribute__((ext_vector_type(4))) float f32x4;

#define B_   4
#define S_   1024
#define D_   1024
#define H_   16
#define DH_  64
#define NOUT_ ((size_t)B_ * S_ * D_)   // 4,194,304 out elems; attn follows in d_out
#define NQ_  4194304                   // elems in q/k/v (and each [B,H,S,64] tensor)
#define NW_  1048576                   // elems in each weight matrix

__device__ __forceinline__ float b2f(u16 u) {
  union { unsigned int u; float f; } v; v.u = ((unsigned int)u) << 16; return v.f;
}
__device__ __forceinline__ u16 f2b(float f) {
  __hip_bfloat16 h = __float2bfloat16(f);
  return *reinterpret_cast<u16*>(&h);
}

// ---------------------------------------------------------------------------
// K0: fp32 -> bf16 conversion of all inputs (one pass, coalesced).
// grid.y = segment (0..6): q,k,v (2048 blocks) / Wq,Wk,Wv,Wd (512 blocks).
// Each block converts 2048 elems (256 thr x 8).
// ---------------------------------------------------------------------------
__global__ __launch_bounds__(256) void convert_kernel(
    const float* __restrict__ q, const float* __restrict__ k, const float* __restrict__ v,
    const float* __restrict__ wq, const float* __restrict__ wk,
    const float* __restrict__ wv, const float* __restrict__ wd,
    u16* __restrict__ qb, u16* __restrict__ kb, u16* __restrict__ vb,
    u16* __restrict__ wqb, u16* __restrict__ wkb, u16* __restrict__ wvb,
    u16* __restrict__ wdb)
{
  const float* src; u16* dst; int nblk;
  switch (blockIdx.y) {
    case 0: src = q;  dst = qb;  nblk = 2048; break;
    case 1: src = k;  dst = kb;  nblk = 2048; break;
    case 2: src = v;  dst = vb;  nblk = 2048; break;
    case 3: src = wq; dst = wqb; nblk = 512;  break;
    case 4: src = wk; dst = wkb; nblk = 512;  break;
    case 5: src = wv; dst = wvb; nblk = 512;  break;
    default: src = wd; dst = wdb; nblk = 512; break;
  }
  if ((int)blockIdx.x >= nblk) return;
  size_t idx = ((size_t)blockIdx.x * 256 + threadIdx.x) * 8;
  f32x4 f0 = *(const f32x4*)&src[idx];
  f32x4 f1 = *(const f32x4*)&src[idx + 4];
  short8 o;
  o[0] = (short)f2b(f0[0]); o[1] = (short)f2b(f0[1]);
  o[2] = (short)f2b(f0[2]); o[3] = (short)f2b(f0[3]);
  o[4] = (short)f2b(f1[0]); o[5] = (short)f2b(f1[1]);
  o[6] = (short)f2b(f1[2]); o[7] = (short)f2b(f1[3]);
  *(short8*)&dst[idx] = o;
}

// ---------------------------------------------------------------------------
// K1: fused Q/K/V projection, 128x128 tile, 4x4 16x16x32 accs per wave.
// grid.x in [0,24): z = x>>3 picks tensor, (x&7)*128 = n-tile; grid.y*128 = m.
// Epilogue: z<2 -> [B,H,S,64]; z==2 -> vhT [B,H,64,S] (transpose fused).
// ---------------------------------------------------------------------------
__global__ __launch_bounds__(256) void proj_kernel(
    const u16* __restrict__ Qb, const u16* __restrict__ Kb, const u16* __restrict__ Vb,
    const u16* __restrict__ Wqb, const u16* __restrict__ Wkb, const u16* __restrict__ Wvb,
    u16* __restrict__ qh, u16* __restrict__ kh, u16* __restrict__ vhT)
{
  __shared__ u16 sA[128][72];   // stride 144 B = 36 dw == bank+4 -> 2-way max
  __shared__ u16 sB[128][72];
  const int t = threadIdx.x;
  const int w = t >> 6, ln = t & 15, quad = (t & 63) >> 4;
  const int wm = (w >> 1) * 64, wn = (w & 1) * 64;
  const int bx = blockIdx.x;
  const int z  = bx >> 3;
  const int n0 = (bx & 7) * 128;
  const int m0 = blockIdx.y * 128;
  const u16* A = (z == 0) ? Qb : (z == 1) ? Kb : Vb;
  const u16* W = (z == 0) ? Wqb : (z == 1) ? Wkb : Wvb;

  f32x4 acc[4][4] = {};
  const int lr = t >> 3, lk = (t & 7) * 8;
  for (int kc = 0; kc < 1024; kc += 64) {
#pragma unroll
    for (int s = 0; s < 4; s++) {
      *(short8*)&sA[lr + 32 * s][lk] =
          *(const short8*)&A[(size_t)(m0 + lr + 32 * s) * 1024 + kc + lk];
      *(short8*)&sB[lr + 32 * s][lk] =
          *(const short8*)&W[(size_t)(n0 + lr + 32 * s) * 1024 + kc + lk];
    }
    __syncthreads();
#pragma unroll
    for (int kk = 0; kk < 64; kk += 32) {
      short8 a[4], bfr[4];
#pragma unroll
      for (int i = 0; i < 4; i++) a[i] = *(const short8*)&sA[wm + i * 16 + ln][kk + quad * 8];
#pragma unroll
      for (int j = 0; j < 4; j++) bfr[j] = *(const short8*)&sB[wn + j * 16 + ln][kk + quad * 8];
#pragma unroll
      for (int i = 0; i < 4; i++)
#pragma unroll
        for (int j = 0; j < 4; j++)
          acc[i][j] = __builtin_amdgcn_mfma_f32_16x16x32_bf16(a[i], bfr[j], acc[i][j], 0, 0, 0);
    }
    __syncthreads();
  }
#pragma unroll
  for (int i = 0; i < 4; i++)
#pragma unroll
    for (int j = 0; j < 4; j++)
#pragma unroll
      for (int r = 0; r < 4; r++) {
        int m = m0 + wm + i * 16 + quad * 4 + r;   // token
        int n = n0 + wn + j * 16 + ln;             // channel
        int bb = m >> 10, s = m & 1023, h = n >> 6, d = n & 63;
        u16 val = f2b(acc[i][j][r]);
        if (z == 2) vhT[(((size_t)bb * H_ + h) * DH_ + d) * S_ + s] = val;
        else if (z == 0) qh[(((size_t)bb * H_ + h) * S_ + s) * DH_ + d] = val;
        else             kh[(((size_t)bb * H_ + h) * S_ + s) * DH_ + d] = val;
      }
}

// ---------------------------------------------------------------------------
// K2: attention. Block = (b,h) x 16 q-rows; 4 waves; 2 barriers total.
// A: QK^T with B-frags loaded straight from global (dense 1KB/wave-instr),
//    scores -> bf16 strip in LDS (stride 1048: <=2-way banks).
// B: vectorized masked softmax, scores/p in regs, coalesced fp32 attn write.
// C: PV with A-frags from strip, V-frags straight from vhT.
// ---------------------------------------------------------------------------
__global__ __launch_bounds__(256) void attn_kernel(
    const u16* __restrict__ qh, const u16* __restrict__ kh,
    const u16* __restrict__ vhT, const int* __restrict__ mask,
    float* __restrict__ attn_out, u16* __restrict__ ctx)
{
  __shared__ u16 s_p[16][1048];   // 33.5 KB
  const int t = threadIdx.x;
  const int w = t >> 6, ln = t & 15, quad = (t & 63) >> 4;
  const int bh = blockIdx.y;
  const int b = bh >> 4, h = bh & 15;
  const int q0 = blockIdx.x * 16;

  // Q A-fragments straight from global: row=ln (q-row), k=quad*8(+32)
  const u16* qbase = qh + ((size_t)bh * S_ + q0) * DH_;
  const short8 aq0 = *(const short8*)&qbase[(size_t)ln * DH_ + quad * 8];
  const short8 aq1 = *(const short8*)&qbase[(size_t)ln * DH_ + 32 + quad * 8];

  // ---- Phase A: scores; wave w owns cols [w*256, w*256+256) ----
  const u16* kbase = kh + (size_t)bh * S_ * DH_;
#pragma unroll
  for (int ck = 0; ck < 16; ck++) {
    int n = w * 256 + ck * 16;
    const u16* krow = &kbase[(size_t)(n + ln) * DH_];
    short8 b0 = *(const short8*)&krow[quad * 8];
    short8 b1 = *(const short8*)&krow[32 + quad * 8];
    f32x4 acc = {};
    acc = __builtin_amdgcn_mfma_f32_16x16x32_bf16(aq0, b0, acc, 0, 0, 0);
    acc = __builtin_amdgcn_mfma_f32_16x16x32_bf16(aq1, b1, acc, 0, 0, 0);
#pragma unroll
    for (int r = 0; r < 4; r++)
      s_p[quad * 4 + r][n + ln] = f2b(acc[r] * 0.03125f);   // 1/sqrt(1024)
  }
  __syncthreads();

  // ---- Phase B: mask + softmax + attn output (16 threads per q-row) ----
  {
    const int r  = t >> 4;    // q-row
    const int cg = t & 15;    // column group: cols cg*8 + 128*i
    const int* mrow = mask + ((size_t)b * S_ + q0 + r) * S_;
    const u16* prow = s_p[r];
    short8 sv[8];
    unsigned long long mbits = 0;
    float mx = -1e30f;
#pragma unroll
    for (int i = 0; i < 8; i++) {
      int c = cg * 8 + i * 128;
      sv[i] = *(const short8*)&prow[c];
      int4 mv0 = *(const int4*)&mrow[c];
      int4 mv1 = *(const int4*)&mrow[c + 4];
      int mm[8] = {mv0.x, mv0.y, mv0.z, mv0.w, mv1.x, mv1.y, mv1.z, mv1.w};
#pragma unroll
      for (int j = 0; j < 8; j++) {
        if (mm[j] != 0) mbits |= (1ull << (i * 8 + j));
        else mx = fmaxf(mx, b2f((u16)sv[i][j]));
      }
    }
#pragma unroll
    for (int off = 8; off >= 1; off >>= 1) mx = fmaxf(mx, __shfl_xor(mx, off));
    float l = 0.f;
#pragma unroll
    for (int i = 0; i < 8; i++) {
      short8 pk;
#pragma unroll
      for (int j = 0; j < 8; j++) {
        float p = ((mbits >> (i * 8 + j)) & 1) ? 0.f
                  : __expf(b2f((u16)sv[i][j]) - mx);
        l += p;
        pk[j] = (short)f2b(p);
      }
      sv[i] = pk;   // regs now hold p (bf16)
    }
#pragma unroll
    for (int off = 8; off >= 1; off >>= 1) l += __shfl_xor(l, off);
    float rinv = (l > 0.f) ? 1.0f / l : 0.f;
    float* arow = attn_out + ((size_t)bh * S_ + q0 + r) * S_;
    u16* prw = s_p[r];
#pragma unroll
    for (int i = 0; i < 8; i++) {
      int c = cg * 8 + i * 128;
      f32x4 o0, o1; short8 pn;
#pragma unroll
      for (int j = 0; j < 8; j++) {
        float pv = b2f((u16)sv[i][j]) * rinv;
        if (j < 4) o0[j] = pv; else o1[j - 4] = pv;
        pn[j] = (short)f2b(pv);
      }
      *(f32x4*)&arow[c] = o0;
      *(f32x4*)&arow[c + 4] = o1;
      *(short8*)&prw[c] = pn;
    }
  }
  __syncthreads();

  // ---- Phase C: ctx = attn @ vh; wave w owns out cols d in [w*16, w*16+16) ----
  f32x4 accC = {};
  const u16* vrow = vhT + ((size_t)bh * DH_ + w * 16 + ln) * S_;
#pragma unroll 4
  for (int kk = 0; kk < 1024; kk += 64) {
    short8 ap0 = *(const short8*)&s_p[ln][kk + quad * 8];
    short8 ap1 = *(const short8*)&s_p[ln][kk + 32 + quad * 8];
    short8 bv0 = *(const short8*)&vrow[kk + quad * 8];
    short8 bv1 = *(const short8*)&vrow[kk + 32 + quad * 8];
    accC = __builtin_amdgcn_mfma_f32_16x16x32_bf16(ap0, bv0, accC, 0, 0, 0);
    accC = __builtin_amdgcn_mfma_f32_16x16x32_bf16(ap1, bv1, accC, 0, 0, 0);
  }
#pragma unroll
  for (int r = 0; r < 4; r++) {
    int qrow = q0 + quad * 4 + r;
    ctx[((size_t)b * S_ + qrow) * D_ + h * DH_ + w * 16 + ln] = f2b(accC[r]);
  }
}

// ---------------------------------------------------------------------------
// K3: out = ctx @ Wd^T + bd (fp32 out). 128x128 tile, same GEMM skeleton.
// ---------------------------------------------------------------------------
__global__ __launch_bounds__(256) void outproj_kernel(
    const u16* __restrict__ ctx, const u16* __restrict__ Wdb,
    const float* __restrict__ bd, float* __restrict__ out)
{
  __shared__ u16 sA[128][72];
  __shared__ u16 sB[128][72];
  const int t = threadIdx.x;
  const int w = t >> 6, ln = t & 15, quad = (t & 63) >> 4;
  const int wm = (w >> 1) * 64, wn = (w & 1) * 64;
  const int n0 = blockIdx.x * 128;
  const int m0 = blockIdx.y * 128;

  f32x4 acc[4][4] = {};
  const int lr = t >> 3, lk = (t & 7) * 8;
  for (int kc = 0; kc < 1024; kc += 64) {
#pragma unroll
    for (int s = 0; s < 4; s++) {
      *(short8*)&sA[lr + 32 * s][lk] =
          *(const short8*)&ctx[(size_t)(m0 + lr + 32 * s) * 1024 + kc + lk];
      *(short8*)&sB[lr + 32 * s][lk] =
          *(const short8*)&Wdb[(size_t)(n0 + lr + 32 * s) * 1024 + kc + lk];
    }
    __syncthreads();
#pragma unroll
    for (int kk = 0; kk < 64; kk += 32) {
      short8 a[4], bfr[4];
#pragma unroll
      for (int i = 0; i < 4; i++) a[i] = *(const short8*)&sA[wm + i * 16 + ln][kk + quad * 8];
#pragma unroll
      for (int j = 0; j < 4; j++) bfr[j] = *(const short8*)&sB[wn + j * 16 + ln][kk + quad * 8];
#pragma unroll
      for (int i = 0; i < 4; i++)
#pragma unroll
        for (int j = 0; j < 4; j++)
          acc[i][j] = __builtin_amdgcn_mfma_f32_16x16x32_bf16(a[i], bfr[j], acc[i][j], 0, 0, 0);
    }
    __syncthreads();
  }
#pragma unroll
  for (int i = 0; i < 4; i++)
#pragma unroll
    for (int j = 0; j < 4; j++)
#pragma unroll
      for (int r = 0; r < 4; r++) {
        int m = m0 + wm + i * 16 + quad * 4 + r;
        int n = n0 + wn + j * 16 + ln;
        out[(size_t)m * 1024 + n] = acc[i][j][r] + bd[n];
      }
}

extern "C" void kernel_launch(void* const* d_in, const int* in_sizes, int n_in,
                              void* d_out, int out_size, void* d_ws, size_t ws_size,
                              hipStream_t stream) {
  const float* q    = (const float*)d_in[0];
  const float* k    = (const float*)d_in[1];
  const float* v    = (const float*)d_in[2];
  const int*   mask = (const int*)d_in[3];
  const float* Wq   = (const float*)d_in[4];
  const float* Wk   = (const float*)d_in[5];
  const float* Wv   = (const float*)d_in[6];
  const float* Wd   = (const float*)d_in[7];
  const float* bd   = (const float*)d_in[8];

  float* out  = (float*)d_out;
  float* attn = out + NOUT_;

  u16* ws   = (u16*)d_ws;
  u16* Qb   = ws;                    // 3x NQ_ bf16 inputs
  u16* Kb   = ws + (size_t)NQ_;
  u16* Vb   = ws + 2 * (size_t)NQ_;
  u16* Wqb  = ws + 3 * (size_t)NQ_;  // 4x NW_ bf16 weights
  u16* Wkb  = Wqb + (size_t)NW_;
  u16* Wvb  = Wqb + 2 * (size_t)NW_;
  u16* Wdb  = Wqb + 3 * (size_t)NW_;
  u16* qh   = Wqb + 4 * (size_t)NW_; // 3x NQ_ projected tensors
  u16* kh   = qh + (size_t)NQ_;
  u16* vhT  = qh + 2 * (size_t)NQ_;
  u16* ctx  = Qb;                    // alias: Qb dead after proj (stream-ordered)

  convert_kernel<<<dim3(2048, 7), 256, 0, stream>>>(q, k, v, Wq, Wk, Wv, Wd,
                                                    Qb, Kb, Vb, Wqb, Wkb, Wvb, Wdb);
  proj_kernel<<<dim3(24, 32), 256, 0, stream>>>(Qb, Kb, Vb, Wqb, Wkb, Wvb, qh, kh, vhT);
  attn_kernel<<<dim3(64, 64), 256, 0, stream>>>(qh, kh, vhT, mask, attn, ctx);
  outproj_kernel<<<dim3(8, 32), 256, 0, stream>>>(ctx, Wdb, bd, out);
}